// Round 7
// baseline (326.502 us; speedup 1.0000x reference)
//
#include <hip/hip_runtime.h>
#include <hip/hip_cooperative_groups.h>

namespace cg = cooperative_groups;

#define HIDDEN 16
// ---- fine-bucket sorted-CSR path ----
#define FB 128          // nodes per fine bucket (power of two)
#define FB_SHIFT 7
#define NBK_MAX 4096    // LDS limit for hist/fill (n <= 524288)
#define FCHUNK 4096     // edges per block in hist/fill
#define FTH 512         // threads in hist/fill/cnt/sortS1 blocks
#define MTH 256         // threads in cooperative mega kernel
#define SCAP 5120       // LDS sorted-segment capacity (mean 4092 + ~16 sd)
#define NXCD 8          // MI355X chiplets (bid%8 -> XCD, round-robin dispatch)
// ---- fallback (split) path ----
#define CB 1024
#define CB_SHIFT 10
#define NCB_MAX 512
#define CHUNK 4096
#define SPL 8
#define BT 1024

// Bijective XCD-affinity mapping: each XCD (bid%8) owns a CONTIGUOUS range of
// chunks, so partial-line writes to a given tmp region merge in one XCD's L2
// instead of ping-ponging between non-coherent L2s. (r2: -18 us)
// LESSON (r5): never do edge-rate GLOBAL atomics — 3.2M random 4B atomics
// cost ~113 us of coherence traffic. Edge-rate atomics must stay in LDS.
__device__ __forceinline__ int xcd_chunk(int bid, int nwg) {
    if (nwg < NXCD) return bid;
    int q = nwg / NXCD, r = nwg % NXCD;
    int x = bid % NXCD, k = bid / NXCD;
    return (x < r ? x * (q + 1) : r * (q + 1) + (x - r) * q) + k;
}

// ======================= fine-bucket path =======================

__global__ void k_zero(unsigned int* a, int na) {
    int i = blockIdx.x * blockDim.x + threadIdx.x;
    if (i < na) a[i] = 0u;
}

// per-chunk per-bucket histogram -> hcT[bucket*nchunk + chunk]
__global__ __launch_bounds__(FTH) void
k_histf(const int* __restrict__ dst, int e, int nbk, int nchunk,
        unsigned int* __restrict__ hcT) {
    __shared__ unsigned int h[NBK_MAX];   // 16 KB
    for (int i = threadIdx.x; i < nbk; i += FTH) h[i] = 0u;
    __syncthreads();
    int c = xcd_chunk(blockIdx.x, nchunk);
    int start = c * FCHUNK;
    int end = min(start + FCHUNK, e);
    if (end - start == FCHUNK) {
        int i = start + threadIdx.x;
#pragma unroll
        for (int k = 0; k < FCHUNK / FTH; k++, i += FTH)
            atomicAdd(&h[((unsigned)dst[i]) >> FB_SHIFT], 1u);
    } else {
        for (int i = start + threadIdx.x; i < end; i += FTH)
            atomicAdd(&h[((unsigned)dst[i]) >> FB_SHIFT], 1u);
    }
    __syncthreads();
    for (int j = threadIdx.x; j < nbk; j += FTH)
        hcT[(size_t)j * nchunk + c] = h[j];
}

// block per bucket: in-place exclusive scan of hcT row -> relative bases;
// total -> cntc.  Serial-4-per-thread (r4: 4x fewer barriers).
__global__ void k_scanf(unsigned int* __restrict__ hcT,
                        unsigned int* __restrict__ cntc, int nchunk) {
    __shared__ unsigned int ps[256];
    __shared__ unsigned int carry;
    int b = blockIdx.x, t = threadIdx.x;
    if (t == 0) carry = 0u;
    __syncthreads();
    size_t row = (size_t)b * nchunk;
    for (int t0 = 0; t0 < nchunk; t0 += 1024) {
        int i0 = t0 + t * 4;
        unsigned v0 = 0, v1 = 0, v2 = 0, v3 = 0;
        if (i0 + 3 < nchunk) {
            v0 = hcT[row + i0];     v1 = hcT[row + i0 + 1];
            v2 = hcT[row + i0 + 2]; v3 = hcT[row + i0 + 3];
        } else {
            if (i0     < nchunk) v0 = hcT[row + i0];
            if (i0 + 1 < nchunk) v1 = hcT[row + i0 + 1];
            if (i0 + 2 < nchunk) v2 = hcT[row + i0 + 2];
            if (i0 + 3 < nchunk) v3 = hcT[row + i0 + 3];
        }
        unsigned s1v = v0 + v1, s2v = s1v + v2, s3v = s2v + v3;
        ps[t] = s3v;
        __syncthreads();
        for (int off = 1; off < 256; off <<= 1) {
            unsigned u = (t >= off) ? ps[t - off] : 0u;
            __syncthreads();
            ps[t] += u;
            __syncthreads();
        }
        unsigned base = carry + ps[t] - s3v;
        if (i0     < nchunk) hcT[row + i0]     = base;
        if (i0 + 1 < nchunk) hcT[row + i0 + 1] = base + v0;
        if (i0 + 2 < nchunk) hcT[row + i0 + 2] = base + s1v;
        if (i0 + 3 < nchunk) hcT[row + i0 + 3] = base + s2v;
        __syncthreads();
        if (t == 255) carry += ps[255];
        __syncthreads();
    }
    if (t == 0) cntc[b] = carry;
}

// exclusive scan of bucket totals -> basec (+ sentinels)
__global__ __launch_bounds__(1024) void
k_scanb(const unsigned int* __restrict__ cntc, int nbk,
        unsigned int* __restrict__ basec,
        unsigned int* __restrict__ rowptr, int n, unsigned int e) {
    __shared__ unsigned int tsum[1024];
    int t = threadIdx.x;
    int K = (nbk + 1023) / 1024;
    unsigned int s = 0;
    for (int k = 0; k < K; k++) {
        int i = t * K + k;
        if (i < nbk) s += cntc[i];
    }
    tsum[t] = s;
    __syncthreads();
    for (int off = 1; off < 1024; off <<= 1) {
        unsigned int v = (t >= off) ? tsum[t - off] : 0u;
        __syncthreads();
        tsum[t] += v;
        __syncthreads();
    }
    unsigned int run = (t == 0) ? 0u : tsum[t - 1];
    for (int k = 0; k < K; k++) {
        int i = t * K + k;
        if (i < nbk) { basec[i] = run; run += cntc[i]; }
    }
    if (t == 1023) basec[nbk] = tsum[1023];  // == e
    if (t == 0) rowptr[n] = e;               // CSR sentinel (old path only)
}

// scatter records (src<<7 | dst&127) using precomputed bases; no cursor atomics.
__global__ __launch_bounds__(FTH) void
k_fillf(const int* __restrict__ src, const int* __restrict__ dst,
        int e, int nbk, int nchunk,
        const unsigned int* __restrict__ basec,
        const unsigned int* __restrict__ hcT,
        unsigned int* __restrict__ tmp) {
    __shared__ unsigned int h[NBK_MAX];    // 16 KB
    __shared__ unsigned int lb[NBK_MAX];   // 16 KB
    int c = xcd_chunk(blockIdx.x, nchunk);
    for (int j = threadIdx.x; j < nbk; j += FTH) {
        lb[j] = basec[j] + hcT[(size_t)j * nchunk + c];
        h[j] = 0u;
    }
    __syncthreads();
    int start = c * FCHUNK;
    int end = min(start + FCHUNK, e);
    if (end - start == FCHUNK) {
        int i = start + threadIdx.x;
#pragma unroll
        for (int k = 0; k < FCHUNK / FTH; k++, i += FTH) {
            unsigned int d = (unsigned)dst[i];
            unsigned int s = (unsigned)src[i];
            unsigned int b = d >> FB_SHIFT;
            unsigned int r = atomicAdd(&h[b], 1u);
            tmp[lb[b] + r] = (s << FB_SHIFT) | (d & (FB - 1u));
        }
    } else {
        for (int i = start + threadIdx.x; i < end; i += FTH) {
            unsigned int d = (unsigned)dst[i];
            unsigned int s = (unsigned)src[i];
            unsigned int b = d >> FB_SHIFT;
            unsigned int r = atomicAdd(&h[b], 1u);
            tmp[lb[b] + r] = (s << FB_SHIFT) | (d & (FB - 1u));
        }
    }
}

// COOPERATIVE mega kernel: block per bucket, bucket state resident in LDS
// across all phases.  P1 count+scan -> xs4 | grid.sync | P2 scatter->lsort
// (tmp re-read same-CU L2-hot) | P3 layer-1 from lsort + fused epilogue |
// grid.sync | P4 layer-2 DIRECTLY from lsort (tmp2 never touched).
// Replaces k_cnt + k_sortS1 + k_s2; eliminates tmp2 + rowptr traffic.
// Residency: __launch_bounds__(256,4) => >=4 blocks/CU (VGPR<=128); LDS
// 22KB => 7/CU; so grid <= 1024 is guaranteed co-resident.
__global__ __launch_bounds__(MTH, 4) void
k_mega(const unsigned int* __restrict__ tmp,
       const unsigned int* __restrict__ basec,
       const float* __restrict__ x,
       float4* __restrict__ xs4,
       const float* __restrict__ W1, const float* __restrict__ b1,
       const float* __restrict__ W2, const float* __restrict__ b2,
       unsigned int* __restrict__ tmp2,   // only for SCAP-overflow fallback
       float* __restrict__ t2s, float* __restrict__ out, int n) {
    cg::grid_group g = cg::this_grid();
    __shared__ unsigned int lsort[SCAP];   // 20 KB, persists P2->P4
    __shared__ unsigned int stn[FB];
    __shared__ unsigned int enn[FB];
    __shared__ unsigned int cur[FB];
    int t = threadIdx.x, b = blockIdx.x;
    unsigned int s = basec[b], endp = basec[b + 1], m = endp - s;
    // ---- P1: count (LDS atomics) + scan + xs4 ----
    if (t < FB) cur[t] = 0u;               // cur doubles as cnt
    __syncthreads();
    {
        unsigned int i = s + t;
        for (; i + 3u * MTH < endp; i += 4u * MTH) {
            unsigned r0 = tmp[i], r1 = tmp[i + MTH], r2 = tmp[i + 2u * MTH], r3 = tmp[i + 3u * MTH];
            atomicAdd(&cur[r0 & (FB - 1u)], 1u);
            atomicAdd(&cur[r1 & (FB - 1u)], 1u);
            atomicAdd(&cur[r2 & (FB - 1u)], 1u);
            atomicAdd(&cur[r3 & (FB - 1u)], 1u);
        }
        for (; i < endp; i += MTH)
            atomicAdd(&cur[tmp[i] & (FB - 1u)], 1u);
    }
    __syncthreads();
    if (t < FB) enn[t] = cur[t];
    __syncthreads();
    for (int off = 1; off < FB; off <<= 1) {               // inclusive scan
        unsigned int v = (t < FB && t >= off) ? enn[t - off] : 0u;
        __syncthreads();
        if (t < FB && t >= off) enn[t] += v;
        __syncthreads();
    }
    if (t < FB) {
        unsigned int c = cur[t];
        unsigned int st = enn[t] - c;
        stn[t] = st;
        cur[t] = st;                                       // scatter cursor
        int node = (b << FB_SHIFT) + t;
        if (node < n) {
            float iv = rsqrtf((float)(1u + c));            // +1 self-loop
            xs4[node] = make_float4(x[3 * node] * iv, x[3 * node + 1] * iv,
                                    x[3 * node + 2] * iv, iv);
        }
    }
    g.sync();                                              // xs4 complete
    // ---- P2: scatter into lsort (tmp re-read is same-CU L2-hot) ----
    bool fits = (m <= SCAP);
    if (fits) {
        unsigned int i = s + t;
        for (; i + 3u * MTH < endp; i += 4u * MTH) {
            unsigned r0 = tmp[i], r1 = tmp[i + MTH], r2 = tmp[i + 2u * MTH], r3 = tmp[i + 3u * MTH];
            unsigned p0 = atomicAdd(&cur[r0 & (FB - 1u)], 1u);
            unsigned p1 = atomicAdd(&cur[r1 & (FB - 1u)], 1u);
            unsigned p2 = atomicAdd(&cur[r2 & (FB - 1u)], 1u);
            unsigned p3 = atomicAdd(&cur[r3 & (FB - 1u)], 1u);
            lsort[p0] = r0 >> FB_SHIFT;
            lsort[p1] = r1 >> FB_SHIFT;
            lsort[p2] = r2 >> FB_SHIFT;
            lsort[p3] = r3 >> FB_SHIFT;
        }
        for (; i < endp; i += MTH) {
            unsigned rec = tmp[i];
            unsigned r = atomicAdd(&cur[rec & (FB - 1u)], 1u);
            lsort[r] = rec >> FB_SHIFT;
        }
    } else {                                               // pathological bucket
        for (unsigned int i = s + t; i < endp; i += MTH) {
            unsigned rec = tmp[i];
            unsigned r = atomicAdd(&cur[rec & (FB - 1u)], 1u);
            tmp2[s + r] = rec >> FB_SHIFT;
        }
    }
    __syncthreads();
    // ---- P3: layer-1 aggregation, 2 threads/node, fused epilogue ----
    int nl = t >> 1, q = t & 1;
    int node = (b << FB_SHIFT) + nl;
    unsigned int st = stn[nl], en = enn[nl];
    float4 me = make_float4(0.f, 0.f, 0.f, 0.f);
    if (node < n) me = xs4[node];
    float v0 = 0.f, v1 = 0.f, v2 = 0.f;
    {
        unsigned int k = st + q;
        if (fits) {
            for (; k + 6 < en; k += 8) {                   // 4-deep ILP
                unsigned a0 = lsort[k], a1 = lsort[k + 2], a2 = lsort[k + 4], a3 = lsort[k + 6];
                float4 p0 = xs4[a0], p1 = xs4[a1], p2 = xs4[a2], p3 = xs4[a3];
                v0 += (p0.x + p1.x) + (p2.x + p3.x);
                v1 += (p0.y + p1.y) + (p2.y + p3.y);
                v2 += (p0.z + p1.z) + (p2.z + p3.z);
            }
            for (; k < en; k += 2) {
                float4 p = xs4[lsort[k]];
                v0 += p.x; v1 += p.y; v2 += p.z;
            }
        } else {
            for (; k < en; k += 2) {
                float4 p = xs4[tmp2[s + k]];
                v0 += p.x; v1 += p.y; v2 += p.z;
            }
        }
    }
    v0 += __shfl_xor(v0, 1);
    v1 += __shfl_xor(v1, 1);
    v2 += __shfl_xor(v2, 1);
    if (q == 0 && node < n) {
        float iv = me.w;
        float w0 = (v0 + me.x) * iv;
        float w1 = (v1 + me.y) * iv;
        float w2 = (v2 + me.z) * iv;
        float acc = 0.f;
#pragma unroll
        for (int k = 0; k < HIDDEN; k++) {
            float hh = fmaxf(fmaf(w0, W1[k], fmaf(w1, W1[HIDDEN + k],
                            fmaf(w2, W1[2 * HIDDEN + k], b1[k]))), 0.f);
            acc += hh * W2[k];
        }
        t2s[node] = acc * iv;
        out[node] = b2[0] + acc * iv * iv;
    }
    g.sync();                                              // t2s complete
    // ---- P4: layer-2 aggregation straight from resident lsort ----
    float v = 0.f;
    {
        unsigned int k = st + q;
        if (fits) {
            for (; k + 6 < en; k += 8)
                v += (t2s[lsort[k]] + t2s[lsort[k + 2]])
                   + (t2s[lsort[k + 4]] + t2s[lsort[k + 6]]);
            for (; k < en; k += 2) v += t2s[lsort[k]];
        } else {
            for (; k < en; k += 2) v += t2s[tmp2[s + k]];
        }
    }
    v += __shfl_xor(v, 1);
    if (q == 0 && node < n) out[node] += v * me.w;
}

// ---- old (non-cooperative) fine tail: used when nbk > 1024 ----

__global__ __launch_bounds__(FTH) void
k_cnt(const unsigned int* __restrict__ tmp,
      const unsigned int* __restrict__ basec,
      const float* __restrict__ x,
      unsigned int* __restrict__ rowptr, float4* __restrict__ xs4, int n) {
    __shared__ unsigned int cnt[FB];
    __shared__ unsigned int sc[FB];
    int t = threadIdx.x, b = blockIdx.x;
    unsigned int s = basec[b], endp = basec[b + 1];
    if (t < FB) cnt[t] = 0u;
    __syncthreads();
    unsigned int i = s + t;
    for (; i + 3u * FTH < endp; i += 4u * FTH) {
        unsigned r0 = tmp[i], r1 = tmp[i + FTH], r2 = tmp[i + 2u * FTH], r3 = tmp[i + 3u * FTH];
        atomicAdd(&cnt[r0 & (FB - 1u)], 1u);
        atomicAdd(&cnt[r1 & (FB - 1u)], 1u);
        atomicAdd(&cnt[r2 & (FB - 1u)], 1u);
        atomicAdd(&cnt[r3 & (FB - 1u)], 1u);
    }
    for (; i < endp; i += FTH)
        atomicAdd(&cnt[tmp[i] & (FB - 1u)], 1u);
    __syncthreads();
    if (t < FB) sc[t] = cnt[t];
    __syncthreads();
    for (int off = 1; off < FB; off <<= 1) {
        unsigned int v = (t < FB && t >= off) ? sc[t - off] : 0u;
        __syncthreads();
        if (t < FB && t >= off) sc[t] += v;
        __syncthreads();
    }
    if (t < FB) {
        int node = (b << FB_SHIFT) + t;
        if (node < n) {
            rowptr[node] = s + sc[t] - cnt[t];
            float iv = rsqrtf((float)(1u + cnt[t]));
            xs4[node] = make_float4(x[3 * node] * iv, x[3 * node + 1] * iv,
                                    x[3 * node + 2] * iv, iv);
        }
    }
}

__global__ __launch_bounds__(FTH) void
k_sortS1(const unsigned int* __restrict__ tmp,
         const unsigned int* __restrict__ basec,
         const unsigned int* __restrict__ rowptr,
         const float4* __restrict__ xs4,
         const float* __restrict__ W1, const float* __restrict__ b1,
         const float* __restrict__ W2, const float* __restrict__ b2,
         unsigned int* __restrict__ tmp2,
         float* __restrict__ t2s, float* __restrict__ out, int n) {
    __shared__ unsigned int lsort[SCAP];
    __shared__ unsigned int stn[FB];
    __shared__ unsigned int enn[FB];
    __shared__ unsigned int cur[FB];
    int t = threadIdx.x, b = blockIdx.x;
    unsigned int s = basec[b], endp = basec[b + 1], m = endp - s;
    if (t < FB) {
        int node = (b << FB_SHIFT) + t;
        unsigned int rp = (node < n) ? rowptr[node] : endp;
        unsigned int rq = (node < n) ? rowptr[node + 1] : endp;
        stn[t] = rp - s; enn[t] = rq - s; cur[t] = rp - s;
    }
    __syncthreads();
    bool fits = (m <= SCAP);
    if (fits) {
        unsigned int i = s + t;
        for (; i + 3u * FTH < endp; i += 4u * FTH) {
            unsigned r0 = tmp[i], r1 = tmp[i + FTH], r2 = tmp[i + 2u * FTH], r3 = tmp[i + 3u * FTH];
            unsigned p0 = atomicAdd(&cur[r0 & (FB - 1u)], 1u);
            unsigned p1 = atomicAdd(&cur[r1 & (FB - 1u)], 1u);
            unsigned p2 = atomicAdd(&cur[r2 & (FB - 1u)], 1u);
            unsigned p3 = atomicAdd(&cur[r3 & (FB - 1u)], 1u);
            lsort[p0] = r0 >> FB_SHIFT;
            lsort[p1] = r1 >> FB_SHIFT;
            lsort[p2] = r2 >> FB_SHIFT;
            lsort[p3] = r3 >> FB_SHIFT;
        }
        for (; i < endp; i += FTH) {
            unsigned rec = tmp[i];
            unsigned r = atomicAdd(&cur[rec & (FB - 1u)], 1u);
            lsort[r] = rec >> FB_SHIFT;
        }
        __syncthreads();
        for (unsigned int k = t; k < m; k += FTH)
            tmp2[s + k] = lsort[k];
    } else {
        for (unsigned int i = s + t; i < endp; i += FTH) {
            unsigned rec = tmp[i];
            unsigned r = atomicAdd(&cur[rec & (FB - 1u)], 1u);
            tmp2[s + r] = rec >> FB_SHIFT;
        }
        __syncthreads();
    }
    int nl = t >> 2, q = t & 3;
    int node = (b << FB_SHIFT) + nl;
    unsigned int st = stn[nl], en = enn[nl];
    float v0 = 0.f, v1 = 0.f, v2 = 0.f;
    if (fits) {
        for (unsigned int k = st + q; k < en; k += 4) {
            float4 p = xs4[lsort[k]];
            v0 += p.x; v1 += p.y; v2 += p.z;
        }
    } else {
        for (unsigned int k = st + q; k < en; k += 4) {
            float4 p = xs4[tmp2[s + k]];
            v0 += p.x; v1 += p.y; v2 += p.z;
        }
    }
    v0 += __shfl_xor(v0, 1); v0 += __shfl_xor(v0, 2);
    v1 += __shfl_xor(v1, 1); v1 += __shfl_xor(v1, 2);
    v2 += __shfl_xor(v2, 1); v2 += __shfl_xor(v2, 2);
    if (q == 0 && node < n) {
        float4 me = xs4[node];
        float iv = me.w;
        v0 = (v0 + me.x) * iv;
        v1 = (v1 + me.y) * iv;
        v2 = (v2 + me.z) * iv;
        float acc = 0.f;
#pragma unroll
        for (int k = 0; k < HIDDEN; k++) {
            float hh = fmaxf(fmaf(v0, W1[k], fmaf(v1, W1[HIDDEN + k],
                            fmaf(v2, W1[2 * HIDDEN + k], b1[k]))), 0.f);
            acc += hh * W2[k];
        }
        t2s[node] = acc * iv;
        out[node] = b2[0] + acc * iv * iv;
    }
}

__global__ void k_s2(const unsigned int* __restrict__ rowptr,
                     const unsigned int* __restrict__ tmp2,
                     const float* __restrict__ t2s, const float4* __restrict__ xs4,
                     float* __restrict__ out, int n) {
    int gid = blockIdx.x * blockDim.x + threadIdx.x;
    int i = gid >> 2, q = gid & 3;
    bool valid = (i < n);
    unsigned int s = 0, epos = 0;
    if (valid) { s = rowptr[i]; epos = rowptr[i + 1]; }
    float v = 0.f;
    unsigned int j = s + q;
    for (; j + 12 < epos; j += 16) {
        unsigned a0 = tmp2[j], a1 = tmp2[j + 4], a2 = tmp2[j + 8], a3 = tmp2[j + 12];
        v += (t2s[a0] + t2s[a1]) + (t2s[a2] + t2s[a3]);
    }
    for (; j < epos; j += 4) v += t2s[tmp2[j]];
    v += __shfl_xor(v, 1); v += __shfl_xor(v, 2);
    if (valid && q == 0) out[i] += v * xs4[i].w;
}

// ======================= split fallback backend =======================

__global__ void k_hist_c(const int* __restrict__ dst, int e, int ncb, int nchunk,
                         unsigned int* __restrict__ cntc,
                         unsigned int* __restrict__ hcT) {
    __shared__ unsigned int h[NCB_MAX];
    for (int i = threadIdx.x; i < ncb; i += blockDim.x) h[i] = 0u;
    __syncthreads();
    int start = blockIdx.x * CHUNK;
    int end = min(start + CHUNK, e);
    for (int i = start + threadIdx.x; i < end; i += 256)
        atomicAdd(&h[((unsigned)dst[i]) >> CB_SHIFT], 1u);
    __syncthreads();
    for (int j = threadIdx.x; j < ncb; j += blockDim.x) {
        hcT[(size_t)j * nchunk + blockIdx.x] = h[j];
        if (h[j]) atomicAdd(&cntc[j], h[j]);
    }
}
__global__ void k_scan(const unsigned int* __restrict__ cnt, int nb,
                       unsigned int* __restrict__ base) {
    __shared__ unsigned int tsum[256];
    int t = threadIdx.x;
    int K = (nb + 255) / 256;
    unsigned int s = 0;
    for (int k = 0; k < K; k++) {
        int i = t * K + k;
        if (i < nb) s += cnt[i];
    }
    tsum[t] = s;
    __syncthreads();
    for (int off = 1; off < 256; off <<= 1) {
        unsigned int v = (t >= off) ? tsum[t - off] : 0u;
        __syncthreads();
        tsum[t] += v;
        __syncthreads();
    }
    unsigned int run = (t == 0) ? 0u : tsum[t - 1];
    for (int k = 0; k < K; k++) {
        int i = t * K + k;
        if (i < nb) { base[i] = run; run += cnt[i]; }
    }
}
__global__ void k_scanc(const unsigned int* __restrict__ hcT,
                        const unsigned int* __restrict__ basec,
                        unsigned int* __restrict__ lbasec, int nchunk) {
    __shared__ unsigned int ts[256];
    __shared__ unsigned int carry;
    int b = blockIdx.x, t = threadIdx.x;
    if (t == 0) carry = basec[b];
    __syncthreads();
    for (int t0 = 0; t0 < nchunk; t0 += 256) {
        int i = t0 + t;
        unsigned int v = (i < nchunk) ? hcT[(size_t)b * nchunk + i] : 0u;
        ts[t] = v;
        __syncthreads();
        for (int off = 1; off < 256; off <<= 1) {
            unsigned int u = (t >= off) ? ts[t - off] : 0u;
            __syncthreads();
            ts[t] += u;
            __syncthreads();
        }
        if (i < nchunk) lbasec[(size_t)b * nchunk + i] = carry + ts[t] - v;
        __syncthreads();
        if (t == 0) carry += ts[255];
        __syncthreads();
    }
}
__global__ void k_fill_c(const int* __restrict__ src, const int* __restrict__ dst,
                         int e, int ncb, int nchunk,
                         const unsigned int* __restrict__ lbasec,
                         unsigned int* __restrict__ tmp) {
    __shared__ unsigned int h[NCB_MAX];
    __shared__ unsigned int lb[NCB_MAX];
    for (int j = threadIdx.x; j < ncb; j += blockDim.x) {
        lb[j] = lbasec[(size_t)j * nchunk + blockIdx.x];
        h[j] = 0u;
    }
    __syncthreads();
    int start = blockIdx.x * CHUNK;
    int end = min(start + CHUNK, e);
    for (int i = start + threadIdx.x; i < end; i += 256) {
        unsigned int d = (unsigned)dst[i];
        unsigned int b = d >> CB_SHIFT;
        unsigned int r = atomicAdd(&h[b], 1u);
        tmp[lb[b] + r] = (((unsigned)src[i]) << CB_SHIFT) | (d & (CB - 1u));
    }
}
__global__ __launch_bounds__(BT) void
k_deg_split(const unsigned int* __restrict__ tmp, const unsigned int* __restrict__ basec,
            const unsigned int* __restrict__ cntc, unsigned int* __restrict__ deg, int n) {
    __shared__ unsigned int degl[CB];
    int t = threadIdx.x;
    degl[t] = 0u;
    __syncthreads();
    int b = blockIdx.x / SPL, sl = blockIdx.x % SPL;
    unsigned int s = basec[b], m = cntc[b];
    for (unsigned int i = sl * BT + t; i < m; i += SPL * BT)
        atomicAdd(&degl[tmp[s + i] & (CB - 1u)], 1u);
    __syncthreads();
    int node = b * CB + t;
    unsigned int c = degl[t];
    if (node < n && c) atomicAdd(&deg[node], c);
}
__global__ void k_inv_s(const unsigned int* __restrict__ deg, const float* __restrict__ x,
                        float4* __restrict__ xs4, int n) {
    int i = blockIdx.x * blockDim.x + threadIdx.x;
    if (i >= n) return;
    float iv = rsqrtf((float)(deg[i] + 1u));
    xs4[i] = make_float4(x[3 * i] * iv, x[3 * i + 1] * iv, x[3 * i + 2] * iv, iv);
}
__global__ __launch_bounds__(BT) void
k_s1_split(const unsigned int* __restrict__ tmp, const unsigned int* __restrict__ basec,
           const unsigned int* __restrict__ cntc, const float4* __restrict__ xs4,
           float* __restrict__ agg0, float* __restrict__ agg1, float* __restrict__ agg2, int n) {
    __shared__ float a0[CB], a1[CB], a2[CB];
    int t = threadIdx.x;
    a0[t] = 0.f; a1[t] = 0.f; a2[t] = 0.f;
    __syncthreads();
    int b = blockIdx.x / SPL, sl = blockIdx.x % SPL;
    unsigned int s = basec[b], m = cntc[b];
    for (unsigned int i = sl * BT + t; i < m; i += SPL * BT) {
        unsigned rec = tmp[s + i];
        float4 v = xs4[rec >> CB_SHIFT];
        unsigned dl = rec & (CB - 1u);
        atomicAdd(&a0[dl], v.x); atomicAdd(&a1[dl], v.y); atomicAdd(&a2[dl], v.z);
    }
    __syncthreads();
    int node = b * CB + t;
    if (node < n) {
        if (a0[t] != 0.f) atomicAdd(&agg0[node], a0[t]);
        if (a1[t] != 0.f) atomicAdd(&agg1[node], a1[t]);
        if (a2[t] != 0.f) atomicAdd(&agg2[node], a2[t]);
    }
}
__global__ void k_epi_s(const float* __restrict__ agg0, const float* __restrict__ agg1,
                        const float* __restrict__ agg2, const float4* __restrict__ xs4,
                        const float* __restrict__ W1, const float* __restrict__ b1,
                        const float* __restrict__ W2, const float* __restrict__ b2,
                        float* __restrict__ t2s, float* __restrict__ out, int n) {
    int i = blockIdx.x * blockDim.x + threadIdx.x;
    if (i >= n) return;
    float4 xv = xs4[i];
    float iv = xv.w;
    float v0 = iv * (agg0[i] + xv.x), v1 = iv * (agg1[i] + xv.y), v2 = iv * (agg2[i] + xv.z);
    float acc = 0.f;
#pragma unroll
    for (int j = 0; j < HIDDEN; j++) {
        float h = fmaxf(fmaf(v0, W1[j], fmaf(v1, W1[HIDDEN + j],
                       fmaf(v2, W1[2 * HIDDEN + j], b1[j]))), 0.f);
        acc += h * W2[j];
    }
    t2s[i] = acc * iv;
    out[i] = b2[0] + acc * iv * iv;
}
__global__ __launch_bounds__(BT) void
k_s2_split(const unsigned int* __restrict__ tmp, const unsigned int* __restrict__ basec,
           const unsigned int* __restrict__ cntc, const float* __restrict__ t2s,
           const float4* __restrict__ xs4, float* __restrict__ out, int n) {
    __shared__ float o[CB];
    int t = threadIdx.x;
    o[t] = 0.f;
    __syncthreads();
    int b = blockIdx.x / SPL, sl = blockIdx.x % SPL;
    unsigned int s = basec[b], m = cntc[b];
    for (unsigned int i = sl * BT + t; i < m; i += SPL * BT) {
        unsigned rec = tmp[s + i];
        atomicAdd(&o[rec & (CB - 1u)], t2s[rec >> CB_SHIFT]);
    }
    __syncthreads();
    int node = b * CB + t;
    if (node < n && o[t] != 0.f) atomicAdd(&out[node], o[t] * xs4[node].w);
}

// ======================= launch =======================

extern "C" void kernel_launch(void* const* d_in, const int* in_sizes, int n_in,
                              void* d_out, int out_size, void* d_ws, size_t ws_size,
                              hipStream_t stream) {
    const float* x  = (const float*)d_in[0];
    const int*   ei = (const int*)d_in[1];
    const float* W1 = (const float*)d_in[2];
    const float* b1 = (const float*)d_in[3];
    const float* W2 = (const float*)d_in[4];
    const float* b2 = (const float*)d_in[5];
    float* out = (float*)d_out;

    int n = in_sizes[0] / 3;
    int e = in_sizes[1] / 2;
    const int* src = ei;
    const int* dst = ei + e;
    const int B = 256;

    int nbk = (n + FB - 1) / FB;
    int nchunkf = (e + FCHUNK - 1) / FCHUNK;
    int gridN4 = (4 * n + B - 1) / B;

    // fine path ws: xs4[n] | t2s[n] | rowptr[n+1] | cntc[nbk] basec[nbk+1]
    //             | hcT[nbk*nchunkf] | tmp[e] | tmp2[e]
    size_t needf = (size_t)n * 16 + (size_t)n * 4 + (size_t)(n + 1) * 4
                 + (size_t)(2 * nbk + 1) * 4 + (size_t)nbk * nchunkf * 4
                 + (size_t)e * 8 + 64;

    if (nbk <= NBK_MAX && n < (1 << 25) && ws_size >= needf) {
        float4* xs4 = (float4*)d_ws;                            // n
        float* t2s = (float*)(xs4 + n);                         // n
        unsigned int* rowptr = (unsigned int*)(t2s + n);        // n+1
        unsigned int* cntc   = rowptr + (n + 1);                // nbk
        unsigned int* basec  = cntc + nbk;                      // nbk+1
        unsigned int* hcT    = basec + nbk + 1;                 // nbk*nchunkf
        unsigned int* tmp    = hcT + (size_t)nbk * nchunkf;     // e
        unsigned int* tmp2   = tmp + e;                         // e

        k_histf<<<nchunkf, FTH, 0, stream>>>(dst, e, nbk, nchunkf, hcT);
        k_scanf<<<nbk, 256, 0, stream>>>(hcT, cntc, nchunkf);
        k_scanb<<<1, 1024, 0, stream>>>(cntc, nbk, basec, rowptr, n, (unsigned)e);
        k_fillf<<<nchunkf, FTH, 0, stream>>>(src, dst, e, nbk, nchunkf, basec, hcT, tmp);
        if (nbk <= 1024) {
            // cooperative path: guaranteed co-resident (>=4 blocks/CU @ 256 thr)
            void* args[] = {(void*)&tmp, (void*)&basec, (void*)&x, (void*)&xs4,
                            (void*)&W1, (void*)&b1, (void*)&W2, (void*)&b2,
                            (void*)&tmp2, (void*)&t2s, (void*)&out, (void*)&n};
            hipLaunchCooperativeKernel((const void*)k_mega, dim3(nbk), dim3(MTH),
                                       args, 0, stream);
        } else {
            k_cnt<<<nbk, FTH, 0, stream>>>(tmp, basec, x, rowptr, xs4, n);
            k_sortS1<<<nbk, FTH, 0, stream>>>(tmp, basec, rowptr, xs4, W1, b1, W2, b2,
                                              tmp2, t2s, out, n);
            k_s2<<<gridN4, B, 0, stream>>>(rowptr, tmp2, t2s, xs4, out, n);
        }
    } else {
        int ncb = (n + CB - 1) / CB;
        int gridE = (e + CHUNK - 1) / CHUNK;
        int gridN = (n + B - 1) / B;
        float4* xs4 = (float4*)d_ws;
        float* agg0 = (float*)(xs4 + n);
        float* agg1 = agg0 + n;
        float* agg2 = agg1 + n;
        unsigned int* deg = (unsigned int*)(agg2 + n);
        float* t2s = (float*)(deg + n);
        unsigned int* cntc   = (unsigned int*)(t2s + n);
        unsigned int* basec  = cntc + ncb;
        unsigned int* hcT    = basec + ncb;
        unsigned int* lbasec = hcT + (size_t)ncb * gridE;
        unsigned int* tmp    = lbasec + (size_t)ncb * gridE;

        k_zero<<<(4 * n + ncb + B - 1) / B, B, 0, stream>>>((unsigned int*)agg0, 4 * n);
        k_zero<<<(ncb + B - 1) / B, B, 0, stream>>>(cntc, ncb);
        k_hist_c<<<gridE, B, 0, stream>>>(dst, e, ncb, gridE, cntc, hcT);
        k_scan<<<1, B, 0, stream>>>(cntc, ncb, basec);
        k_scanc<<<ncb, B, 0, stream>>>(hcT, basec, lbasec, gridE);
        k_fill_c<<<gridE, B, 0, stream>>>(src, dst, e, ncb, gridE, lbasec, tmp);
        k_deg_split<<<ncb * SPL, BT, 0, stream>>>(tmp, basec, cntc, deg, n);
        k_inv_s<<<gridN, B, 0, stream>>>(deg, x, xs4, n);
        k_s1_split<<<ncb * SPL, BT, 0, stream>>>(tmp, basec, cntc, xs4, agg0, agg1, agg2, n);
        k_epi_s<<<gridN, B, 0, stream>>>(agg0, agg1, agg2, xs4, W1, b1, W2, b2, t2s, out, n);
        k_s2_split<<<ncb * SPL, BT, 0, stream>>>(tmp, basec, cntc, t2s, xs4, out, n);
    }
}

// Round 10
// 158.549 us; speedup vs baseline: 2.0593x; 2.0593x over previous
//
#include <hip/hip_runtime.h>

#define HIDDEN 16
// ---- fine-bucket sorted-CSR path ----
#define FB 128          // nodes per fine bucket (power of two)
#define FB_SHIFT 7
#define NBK_MAX 4096    // LDS limit for hist/fill (n <= 524288)
#define FCHUNK 4096     // edges per block in hist/fill
#define FTH 512         // threads in hist/fill/cnt/sortS1 blocks
#define SCAP 5120       // LDS sorted-segment capacity (mean 4092 + ~16 sd)
#define NXCD 8          // MI355X chiplets (bid%8 -> XCD, round-robin dispatch)
// ---- fallback (split) path ----
#define CB 1024
#define CB_SHIFT 10
#define NCB_MAX 512
#define CHUNK 4096
#define SPL 8
#define BT 1024

// Bijective XCD-affinity mapping: each XCD (bid%8) owns a CONTIGUOUS range of
// chunks, so partial-line writes to a given tmp region merge in one XCD's L2
// instead of ping-ponging between non-coherent L2s. (r2: -18 us)
// LESSON (r5): never do edge-rate GLOBAL atomics — coherence traffic ~8x.
// LESSON (r7): no grid.sync mega-kernels — phase serialization + halved
// occupancy cost 3x; kernel boundaries are cheaper.
// LESSON (r8/r9): xs4 is gathered by DATA-DEPENDENT index (src node) in the
// s1 aggregation — any block may read any node's xs4.  xs4 production
// (k_cnt) and consumption (k_sortS1) MUST be separated by a kernel boundary;
// merging them races (absmax 4e-2).  Enumerate cross-block deps before fusing.
__device__ __forceinline__ int xcd_chunk(int bid, int nwg) {
    if (nwg < NXCD) return bid;
    int q = nwg / NXCD, r = nwg % NXCD;
    int x = bid % NXCD, k = bid / NXCD;
    return (x < r ? x * (q + 1) : r * (q + 1) + (x - r) * q) + k;
}

// ======================= fine-bucket path =======================

__global__ void k_zero(unsigned int* a, int na) {
    int i = blockIdx.x * blockDim.x + threadIdx.x;
    if (i < na) a[i] = 0u;
}

// per-chunk per-bucket histogram -> hcT[bucket*nchunk + chunk]
__global__ __launch_bounds__(FTH) void
k_histf(const int* __restrict__ dst, int e, int nbk, int nchunk,
        unsigned int* __restrict__ hcT) {
    __shared__ unsigned int h[NBK_MAX];   // 16 KB
    for (int i = threadIdx.x; i < nbk; i += FTH) h[i] = 0u;
    __syncthreads();
    int c = xcd_chunk(blockIdx.x, nchunk);
    int start = c * FCHUNK;
    int end = min(start + FCHUNK, e);
    if (end - start == FCHUNK) {
        int i = start + threadIdx.x;
#pragma unroll
        for (int k = 0; k < FCHUNK / FTH; k++, i += FTH)
            atomicAdd(&h[((unsigned)dst[i]) >> FB_SHIFT], 1u);
    } else {
        for (int i = start + threadIdx.x; i < end; i += FTH)
            atomicAdd(&h[((unsigned)dst[i]) >> FB_SHIFT], 1u);
    }
    __syncthreads();
    for (int j = threadIdx.x; j < nbk; j += FTH)
        hcT[(size_t)j * nchunk + c] = h[j];
}

// block per bucket: in-place exclusive scan of hcT row -> relative bases;
// total -> cntc.  Serial-4-per-thread (r4: 4x fewer barriers).
__global__ void k_scanf(unsigned int* __restrict__ hcT,
                        unsigned int* __restrict__ cntc, int nchunk) {
    __shared__ unsigned int ps[256];
    __shared__ unsigned int carry;
    int b = blockIdx.x, t = threadIdx.x;
    if (t == 0) carry = 0u;
    __syncthreads();
    size_t row = (size_t)b * nchunk;
    for (int t0 = 0; t0 < nchunk; t0 += 1024) {
        int i0 = t0 + t * 4;
        unsigned v0 = 0, v1 = 0, v2 = 0, v3 = 0;
        if (i0 + 3 < nchunk) {
            v0 = hcT[row + i0];     v1 = hcT[row + i0 + 1];
            v2 = hcT[row + i0 + 2]; v3 = hcT[row + i0 + 3];
        } else {
            if (i0     < nchunk) v0 = hcT[row + i0];
            if (i0 + 1 < nchunk) v1 = hcT[row + i0 + 1];
            if (i0 + 2 < nchunk) v2 = hcT[row + i0 + 2];
            if (i0 + 3 < nchunk) v3 = hcT[row + i0 + 3];
        }
        unsigned s1v = v0 + v1, s2v = s1v + v2, s3v = s2v + v3;
        ps[t] = s3v;
        __syncthreads();
        for (int off = 1; off < 256; off <<= 1) {
            unsigned u = (t >= off) ? ps[t - off] : 0u;
            __syncthreads();
            ps[t] += u;
            __syncthreads();
        }
        unsigned base = carry + ps[t] - s3v;
        if (i0     < nchunk) hcT[row + i0]     = base;
        if (i0 + 1 < nchunk) hcT[row + i0 + 1] = base + v0;
        if (i0 + 2 < nchunk) hcT[row + i0 + 2] = base + s1v;
        if (i0 + 3 < nchunk) hcT[row + i0 + 3] = base + s2v;
        __syncthreads();
        if (t == 255) carry += ps[255];
        __syncthreads();
    }
    if (t == 0) cntc[b] = carry;
}

// exclusive scan of bucket totals -> basec (+ sentinels)
__global__ __launch_bounds__(1024) void
k_scanb(const unsigned int* __restrict__ cntc, int nbk,
        unsigned int* __restrict__ basec,
        unsigned int* __restrict__ rowptr, int n, unsigned int e) {
    __shared__ unsigned int tsum[1024];
    int t = threadIdx.x;
    int K = (nbk + 1023) / 1024;
    unsigned int s = 0;
    for (int k = 0; k < K; k++) {
        int i = t * K + k;
        if (i < nbk) s += cntc[i];
    }
    tsum[t] = s;
    __syncthreads();
    for (int off = 1; off < 1024; off <<= 1) {
        unsigned int v = (t >= off) ? tsum[t - off] : 0u;
        __syncthreads();
        tsum[t] += v;
        __syncthreads();
    }
    unsigned int run = (t == 0) ? 0u : tsum[t - 1];
    for (int k = 0; k < K; k++) {
        int i = t * K + k;
        if (i < nbk) { basec[i] = run; run += cntc[i]; }
    }
    if (t == 1023) basec[nbk] = tsum[1023];  // == e
    if (t == 0) rowptr[n] = e;               // CSR sentinel
}

// scatter records (src<<7 | dst&127) using precomputed bases; no cursor atomics.
__global__ __launch_bounds__(FTH) void
k_fillf(const int* __restrict__ src, const int* __restrict__ dst,
        int e, int nbk, int nchunk,
        const unsigned int* __restrict__ basec,
        const unsigned int* __restrict__ hcT,
        unsigned int* __restrict__ tmp) {
    __shared__ unsigned int h[NBK_MAX];    // 16 KB
    __shared__ unsigned int lb[NBK_MAX];   // 16 KB
    int c = xcd_chunk(blockIdx.x, nchunk);
    for (int j = threadIdx.x; j < nbk; j += FTH) {
        lb[j] = basec[j] + hcT[(size_t)j * nchunk + c];
        h[j] = 0u;
    }
    __syncthreads();
    int start = c * FCHUNK;
    int end = min(start + FCHUNK, e);
    if (end - start == FCHUNK) {
        int i = start + threadIdx.x;
#pragma unroll
        for (int k = 0; k < FCHUNK / FTH; k++, i += FTH) {
            unsigned int d = (unsigned)dst[i];
            unsigned int s = (unsigned)src[i];
            unsigned int b = d >> FB_SHIFT;
            unsigned int r = atomicAdd(&h[b], 1u);
            tmp[lb[b] + r] = (s << FB_SHIFT) | (d & (FB - 1u));
        }
    } else {
        for (int i = start + threadIdx.x; i < end; i += FTH) {
            unsigned int d = (unsigned)dst[i];
            unsigned int s = (unsigned)src[i];
            unsigned int b = d >> FB_SHIFT;
            unsigned int r = atomicAdd(&h[b], 1u);
            tmp[lb[b] + r] = (s << FB_SHIFT) | (d & (FB - 1u));
        }
    }
}

// per-bucket count pass (LDS atomics) -> in-bucket scan -> rowptr + xs4.
// Split from the scatter so xs4 is globally COMPLETE at the next kernel
// boundary (s1 gathers xs4 by data-dependent index — see r8/r9 lesson).
__global__ __launch_bounds__(FTH) void
k_cnt(const unsigned int* __restrict__ tmp,
      const unsigned int* __restrict__ basec,
      const float* __restrict__ x,
      unsigned int* __restrict__ rowptr, float4* __restrict__ xs4, int n) {
    __shared__ unsigned int cnt[FB];
    __shared__ unsigned int sc[FB];
    int t = threadIdx.x, b = blockIdx.x;
    unsigned int s = basec[b], endp = basec[b + 1];
    if (t < FB) cnt[t] = 0u;
    __syncthreads();
    unsigned int i = s + t;
    for (; i + 3u * FTH < endp; i += 4u * FTH) {
        unsigned r0 = tmp[i], r1 = tmp[i + FTH], r2 = tmp[i + 2u * FTH], r3 = tmp[i + 3u * FTH];
        atomicAdd(&cnt[r0 & (FB - 1u)], 1u);
        atomicAdd(&cnt[r1 & (FB - 1u)], 1u);
        atomicAdd(&cnt[r2 & (FB - 1u)], 1u);
        atomicAdd(&cnt[r3 & (FB - 1u)], 1u);
    }
    for (; i < endp; i += FTH)
        atomicAdd(&cnt[tmp[i] & (FB - 1u)], 1u);
    __syncthreads();
    if (t < FB) sc[t] = cnt[t];
    __syncthreads();
    for (int off = 1; off < FB; off <<= 1) {               // inclusive scan
        unsigned int v = (t < FB && t >= off) ? sc[t - off] : 0u;
        __syncthreads();
        if (t < FB && t >= off) sc[t] += v;
        __syncthreads();
    }
    if (t < FB) {
        int node = (b << FB_SHIFT) + t;
        if (node < n) {
            rowptr[node] = s + sc[t] - cnt[t];
            float iv = rsqrtf((float)(1u + cnt[t]));       // +1 self-loop
            xs4[node] = make_float4(x[3 * node] * iv, x[3 * node + 1] * iv,
                                    x[3 * node + 2] * iv, iv);
        }
    }
}

// FUSED scatter + layer-1: run boundaries come from rowptr (k_cnt), scatter
// into LDS (cap SCAP, global fallback), stream tmp2 coalesced for k_s2, then
// aggregate layer-1 from the LDS-sorted runs (4 threads/node, shfl combine,
// fused W1/ReLU/W2 epilogue).  The VMEM gather phase of one resident block
// overlaps the DS-atomic scatter phase of its neighbors (m114 pipe overlap).
__global__ __launch_bounds__(FTH) void
k_sortS1(const unsigned int* __restrict__ tmp,
         const unsigned int* __restrict__ basec,
         const unsigned int* __restrict__ rowptr,
         const float4* __restrict__ xs4,
         const float* __restrict__ W1, const float* __restrict__ b1,
         const float* __restrict__ W2, const float* __restrict__ b2,
         unsigned int* __restrict__ tmp2,
         float* __restrict__ t2s, float* __restrict__ out, int n) {
    __shared__ unsigned int lsort[SCAP];   // 20 KB sorted segment
    __shared__ unsigned int stn[FB];
    __shared__ unsigned int enn[FB];
    __shared__ unsigned int cur[FB];
    int t = threadIdx.x, b = blockIdx.x;
    unsigned int s = basec[b], endp = basec[b + 1], m = endp - s;
    if (t < FB) {
        int node = (b << FB_SHIFT) + t;
        unsigned int rp = (node < n) ? rowptr[node] : endp;      // rel-to-s below
        unsigned int rq = (node < n) ? rowptr[node + 1] : endp;  // rowptr[n]=e sentinel
        stn[t] = rp - s; enn[t] = rq - s; cur[t] = rp - s;
    }
    __syncthreads();
    bool fits = (m <= SCAP);
    if (fits) {
        unsigned int i = s + t;
        for (; i + 3u * FTH < endp; i += 4u * FTH) {       // scatter -> LDS, 4-deep
            unsigned r0 = tmp[i], r1 = tmp[i + FTH], r2 = tmp[i + 2u * FTH], r3 = tmp[i + 3u * FTH];
            unsigned p0 = atomicAdd(&cur[r0 & (FB - 1u)], 1u);
            unsigned p1 = atomicAdd(&cur[r1 & (FB - 1u)], 1u);
            unsigned p2 = atomicAdd(&cur[r2 & (FB - 1u)], 1u);
            unsigned p3 = atomicAdd(&cur[r3 & (FB - 1u)], 1u);
            lsort[p0] = r0 >> FB_SHIFT;
            lsort[p1] = r1 >> FB_SHIFT;
            lsort[p2] = r2 >> FB_SHIFT;
            lsort[p3] = r3 >> FB_SHIFT;
        }
        for (; i < endp; i += FTH) {
            unsigned rec = tmp[i];
            unsigned r = atomicAdd(&cur[rec & (FB - 1u)], 1u);
            lsort[r] = rec >> FB_SHIFT;
        }
        __syncthreads();
        for (unsigned int k = t; k < m; k += FTH)          // coalesced stream
            tmp2[s + k] = lsort[k];
    } else {                                               // pathological bucket
        for (unsigned int i = s + t; i < endp; i += FTH) {
            unsigned rec = tmp[i];
            unsigned r = atomicAdd(&cur[rec & (FB - 1u)], 1u);
            tmp2[s + r] = rec >> FB_SHIFT;
        }
        __syncthreads();
    }
    // ---- layer-1 aggregation: 4 threads per node ----
    int nl = t >> 2, q = t & 3;                            // nl in [0,128)
    int node = (b << FB_SHIFT) + nl;
    unsigned int st = stn[nl], en = enn[nl];
    float v0 = 0.f, v1 = 0.f, v2 = 0.f;
    if (fits) {
        for (unsigned int k = st + q; k < en; k += 4) {
            float4 p = xs4[lsort[k]];
            v0 += p.x; v1 += p.y; v2 += p.z;
        }
    } else {
        for (unsigned int k = st + q; k < en; k += 4) {
            float4 p = xs4[tmp2[s + k]];
            v0 += p.x; v1 += p.y; v2 += p.z;
        }
    }
    v0 += __shfl_xor(v0, 1); v0 += __shfl_xor(v0, 2);
    v1 += __shfl_xor(v1, 1); v1 += __shfl_xor(v1, 2);
    v2 += __shfl_xor(v2, 1); v2 += __shfl_xor(v2, 2);
    if (q == 0 && node < n) {
        float4 me = xs4[node];
        float iv = me.w;
        v0 = (v0 + me.x) * iv;
        v1 = (v1 + me.y) * iv;
        v2 = (v2 + me.z) * iv;
        float acc = 0.f;
#pragma unroll
        for (int k = 0; k < HIDDEN; k++) {
            float hh = fmaxf(fmaf(v0, W1[k], fmaf(v1, W1[HIDDEN + k],
                            fmaf(v2, W1[2 * HIDDEN + k], b1[k]))), 0.f);
            acc += hh * W2[k];
        }
        t2s[node] = acc * iv;
        out[node] = b2[0] + acc * iv * iv;
    }
}

// layer-2: four threads per node, scalar t2s gathers, two shfl_xor combines
__global__ void k_s2(const unsigned int* __restrict__ rowptr,
                     const unsigned int* __restrict__ tmp2,
                     const float* __restrict__ t2s, const float4* __restrict__ xs4,
                     float* __restrict__ out, int n) {
    int gid = blockIdx.x * blockDim.x + threadIdx.x;
    int i = gid >> 2, q = gid & 3;
    bool valid = (i < n);
    unsigned int s = 0, epos = 0;
    if (valid) { s = rowptr[i]; epos = rowptr[i + 1]; }
    float v = 0.f;
    unsigned int j = s + q;
    for (; j + 12 < epos; j += 16) {
        unsigned a0 = tmp2[j], a1 = tmp2[j + 4], a2 = tmp2[j + 8], a3 = tmp2[j + 12];
        v += (t2s[a0] + t2s[a1]) + (t2s[a2] + t2s[a3]);
    }
    for (; j < epos; j += 4) v += t2s[tmp2[j]];
    v += __shfl_xor(v, 1); v += __shfl_xor(v, 2);
    if (valid && q == 0) out[i] += v * xs4[i].w;
}

// ======================= split fallback backend =======================

__global__ void k_hist_c(const int* __restrict__ dst, int e, int ncb, int nchunk,
                         unsigned int* __restrict__ cntc,
                         unsigned int* __restrict__ hcT) {
    __shared__ unsigned int h[NCB_MAX];
    for (int i = threadIdx.x; i < ncb; i += blockDim.x) h[i] = 0u;
    __syncthreads();
    int start = blockIdx.x * CHUNK;
    int end = min(start + CHUNK, e);
    for (int i = start + threadIdx.x; i < end; i += 256)
        atomicAdd(&h[((unsigned)dst[i]) >> CB_SHIFT], 1u);
    __syncthreads();
    for (int j = threadIdx.x; j < ncb; j += blockDim.x) {
        hcT[(size_t)j * nchunk + blockIdx.x] = h[j];
        if (h[j]) atomicAdd(&cntc[j], h[j]);
    }
}
__global__ void k_scan(const unsigned int* __restrict__ cnt, int nb,
                       unsigned int* __restrict__ base) {
    __shared__ unsigned int tsum[256];
    int t = threadIdx.x;
    int K = (nb + 255) / 256;
    unsigned int s = 0;
    for (int k = 0; k < K; k++) {
        int i = t * K + k;
        if (i < nb) s += cnt[i];
    }
    tsum[t] = s;
    __syncthreads();
    for (int off = 1; off < 256; off <<= 1) {
        unsigned int v = (t >= off) ? tsum[t - off] : 0u;
        __syncthreads();
        tsum[t] += v;
        __syncthreads();
    }
    unsigned int run = (t == 0) ? 0u : tsum[t - 1];
    for (int k = 0; k < K; k++) {
        int i = t * K + k;
        if (i < nb) { base[i] = run; run += cnt[i]; }
    }
}
__global__ void k_scanc(const unsigned int* __restrict__ hcT,
                        const unsigned int* __restrict__ basec,
                        unsigned int* __restrict__ lbasec, int nchunk) {
    __shared__ unsigned int ts[256];
    __shared__ unsigned int carry;
    int b = blockIdx.x, t = threadIdx.x;
    if (t == 0) carry = basec[b];
    __syncthreads();
    for (int t0 = 0; t0 < nchunk; t0 += 256) {
        int i = t0 + t;
        unsigned int v = (i < nchunk) ? hcT[(size_t)b * nchunk + i] : 0u;
        ts[t] = v;
        __syncthreads();
        for (int off = 1; off < 256; off <<= 1) {
            unsigned int u = (t >= off) ? ts[t - off] : 0u;
            __syncthreads();
            ts[t] += u;
            __syncthreads();
        }
        if (i < nchunk) lbasec[(size_t)b * nchunk + i] = carry + ts[t] - v;
        __syncthreads();
        if (t == 0) carry += ts[255];
        __syncthreads();
    }
}
__global__ void k_fill_c(const int* __restrict__ src, const int* __restrict__ dst,
                         int e, int ncb, int nchunk,
                         const unsigned int* __restrict__ lbasec,
                         unsigned int* __restrict__ tmp) {
    __shared__ unsigned int h[NCB_MAX];
    __shared__ unsigned int lb[NCB_MAX];
    for (int j = threadIdx.x; j < ncb; j += blockDim.x) {
        lb[j] = lbasec[(size_t)j * nchunk + blockIdx.x];
        h[j] = 0u;
    }
    __syncthreads();
    int start = blockIdx.x * CHUNK;
    int end = min(start + CHUNK, e);
    for (int i = start + threadIdx.x; i < end; i += 256) {
        unsigned int d = (unsigned)dst[i];
        unsigned int b = d >> CB_SHIFT;
        unsigned int r = atomicAdd(&h[b], 1u);
        tmp[lb[b] + r] = (((unsigned)src[i]) << CB_SHIFT) | (d & (CB - 1u));
    }
}
__global__ __launch_bounds__(BT) void
k_deg_split(const unsigned int* __restrict__ tmp, const unsigned int* __restrict__ basec,
            const unsigned int* __restrict__ cntc, unsigned int* __restrict__ deg, int n) {
    __shared__ unsigned int degl[CB];
    int t = threadIdx.x;
    degl[t] = 0u;
    __syncthreads();
    int b = blockIdx.x / SPL, sl = blockIdx.x % SPL;
    unsigned int s = basec[b], m = cntc[b];
    for (unsigned int i = sl * BT + t; i < m; i += SPL * BT)
        atomicAdd(&degl[tmp[s + i] & (CB - 1u)], 1u);
    __syncthreads();
    int node = b * CB + t;
    unsigned int c = degl[t];
    if (node < n && c) atomicAdd(&deg[node], c);
}
__global__ void k_inv_s(const unsigned int* __restrict__ deg, const float* __restrict__ x,
                        float4* __restrict__ xs4, int n) {
    int i = blockIdx.x * blockDim.x + threadIdx.x;
    if (i >= n) return;
    float iv = rsqrtf((float)(deg[i] + 1u));
    xs4[i] = make_float4(x[3 * i] * iv, x[3 * i + 1] * iv, x[3 * i + 2] * iv, iv);
}
__global__ __launch_bounds__(BT) void
k_s1_split(const unsigned int* __restrict__ tmp, const unsigned int* __restrict__ basec,
           const unsigned int* __restrict__ cntc, const float4* __restrict__ xs4,
           float* __restrict__ agg0, float* __restrict__ agg1, float* __restrict__ agg2, int n) {
    __shared__ float a0[CB], a1[CB], a2[CB];
    int t = threadIdx.x;
    a0[t] = 0.f; a1[t] = 0.f; a2[t] = 0.f;
    __syncthreads();
    int b = blockIdx.x / SPL, sl = blockIdx.x % SPL;
    unsigned int s = basec[b], m = cntc[b];
    for (unsigned int i = sl * BT + t; i < m; i += SPL * BT) {
        unsigned rec = tmp[s + i];
        float4 v = xs4[rec >> CB_SHIFT];
        unsigned dl = rec & (CB - 1u);
        atomicAdd(&a0[dl], v.x); atomicAdd(&a1[dl], v.y); atomicAdd(&a2[dl], v.z);
    }
    __syncthreads();
    int node = b * CB + t;
    if (node < n) {
        if (a0[t] != 0.f) atomicAdd(&agg0[node], a0[t]);
        if (a1[t] != 0.f) atomicAdd(&agg1[node], a1[t]);
        if (a2[t] != 0.f) atomicAdd(&agg2[node], a2[t]);
    }
}
__global__ void k_epi_s(const float* __restrict__ agg0, const float* __restrict__ agg1,
                        const float* __restrict__ agg2, const float4* __restrict__ xs4,
                        const float* __restrict__ W1, const float* __restrict__ b1,
                        const float* __restrict__ W2, const float* __restrict__ b2,
                        float* __restrict__ t2s, float* __restrict__ out, int n) {
    int i = blockIdx.x * blockDim.x + threadIdx.x;
    if (i >= n) return;
    float4 xv = xs4[i];
    float iv = xv.w;
    float v0 = iv * (agg0[i] + xv.x), v1 = iv * (agg1[i] + xv.y), v2 = iv * (agg2[i] + xv.z);
    float acc = 0.f;
#pragma unroll
    for (int j = 0; j < HIDDEN; j++) {
        float h = fmaxf(fmaf(v0, W1[j], fmaf(v1, W1[HIDDEN + j],
                       fmaf(v2, W1[2 * HIDDEN + j], b1[j]))), 0.f);
        acc += h * W2[j];
    }
    t2s[i] = acc * iv;
    out[i] = b2[0] + acc * iv * iv;
}
__global__ __launch_bounds__(BT) void
k_s2_split(const unsigned int* __restrict__ tmp, const unsigned int* __restrict__ basec,
           const unsigned int* __restrict__ cntc, const float* __restrict__ t2s,
           const float4* __restrict__ xs4, float* __restrict__ out, int n) {
    __shared__ float o[CB];
    int t = threadIdx.x;
    o[t] = 0.f;
    __syncthreads();
    int b = blockIdx.x / SPL, sl = blockIdx.x % SPL;
    unsigned int s = basec[b], m = cntc[b];
    for (unsigned int i = sl * BT + t; i < m; i += SPL * BT) {
        unsigned rec = tmp[s + i];
        atomicAdd(&o[rec & (CB - 1u)], t2s[rec >> CB_SHIFT]);
    }
    __syncthreads();
    int node = b * CB + t;
    if (node < n && o[t] != 0.f) atomicAdd(&out[node], o[t] * xs4[node].w);
}

// ======================= launch =======================

extern "C" void kernel_launch(void* const* d_in, const int* in_sizes, int n_in,
                              void* d_out, int out_size, void* d_ws, size_t ws_size,
                              hipStream_t stream) {
    const float* x  = (const float*)d_in[0];
    const int*   ei = (const int*)d_in[1];
    const float* W1 = (const float*)d_in[2];
    const float* b1 = (const float*)d_in[3];
    const float* W2 = (const float*)d_in[4];
    const float* b2 = (const float*)d_in[5];
    float* out = (float*)d_out;

    int n = in_sizes[0] / 3;
    int e = in_sizes[1] / 2;
    const int* src = ei;
    const int* dst = ei + e;
    const int B = 256;

    int nbk = (n + FB - 1) / FB;
    int nchunkf = (e + FCHUNK - 1) / FCHUNK;
    int gridN4 = (4 * n + B - 1) / B;

    // fine path ws: xs4[n] | t2s[n] | rowptr[n+1] | cntc[nbk] basec[nbk+1]
    //             | hcT[nbk*nchunkf] | tmp[e] | tmp2[e]
    size_t needf = (size_t)n * 16 + (size_t)n * 4 + (size_t)(n + 1) * 4
                 + (size_t)(2 * nbk + 1) * 4 + (size_t)nbk * nchunkf * 4
                 + (size_t)e * 8 + 64;

    if (nbk <= NBK_MAX && n < (1 << 25) && ws_size >= needf) {
        float4* xs4 = (float4*)d_ws;                            // n
        float* t2s = (float*)(xs4 + n);                         // n
        unsigned int* rowptr = (unsigned int*)(t2s + n);        // n+1
        unsigned int* cntc   = rowptr + (n + 1);                // nbk
        unsigned int* basec  = cntc + nbk;                      // nbk+1
        unsigned int* hcT    = basec + nbk + 1;                 // nbk*nchunkf
        unsigned int* tmp    = hcT + (size_t)nbk * nchunkf;     // e
        unsigned int* tmp2   = tmp + e;                         // e

        k_histf<<<nchunkf, FTH, 0, stream>>>(dst, e, nbk, nchunkf, hcT);
        k_scanf<<<nbk, 256, 0, stream>>>(hcT, cntc, nchunkf);
        k_scanb<<<1, 1024, 0, stream>>>(cntc, nbk, basec, rowptr, n, (unsigned)e);
        k_fillf<<<nchunkf, FTH, 0, stream>>>(src, dst, e, nbk, nchunkf, basec, hcT, tmp);
        k_cnt<<<nbk, FTH, 0, stream>>>(tmp, basec, x, rowptr, xs4, n);
        k_sortS1<<<nbk, FTH, 0, stream>>>(tmp, basec, rowptr, xs4, W1, b1, W2, b2,
                                          tmp2, t2s, out, n);
        k_s2<<<gridN4, B, 0, stream>>>(rowptr, tmp2, t2s, xs4, out, n);
    } else {
        int ncb = (n + CB - 1) / CB;
        int gridE = (e + CHUNK - 1) / CHUNK;
        int gridN = (n + B - 1) / B;
        float4* xs4 = (float4*)d_ws;
        float* agg0 = (float*)(xs4 + n);
        float* agg1 = agg0 + n;
        float* agg2 = agg1 + n;
        unsigned int* deg = (unsigned int*)(agg2 + n);
        float* t2s = (float*)(deg + n);
        unsigned int* cntc   = (unsigned int*)(t2s + n);
        unsigned int* basec  = cntc + ncb;
        unsigned int* hcT    = basec + ncb;
        unsigned int* lbasec = hcT + (size_t)ncb * gridE;
        unsigned int* tmp    = lbasec + (size_t)ncb * gridE;

        k_zero<<<(4 * n + ncb + B - 1) / B, B, 0, stream>>>((unsigned int*)agg0, 4 * n);
        k_zero<<<(ncb + B - 1) / B, B, 0, stream>>>(cntc, ncb);
        k_hist_c<<<gridE, B, 0, stream>>>(dst, e, ncb, gridE, cntc, hcT);
        k_scan<<<1, B, 0, stream>>>(cntc, ncb, basec);
        k_scanc<<<ncb, B, 0, stream>>>(hcT, basec, lbasec, gridE);
        k_fill_c<<<gridE, B, 0, stream>>>(src, dst, e, ncb, gridE, lbasec, tmp);
        k_deg_split<<<ncb * SPL, BT, 0, stream>>>(tmp, basec, cntc, deg, n);
        k_inv_s<<<gridN, B, 0, stream>>>(deg, x, xs4, n);
        k_s1_split<<<ncb * SPL, BT, 0, stream>>>(tmp, basec, cntc, xs4, agg0, agg1, agg2, n);
        k_epi_s<<<gridN, B, 0, stream>>>(agg0, agg1, agg2, xs4, W1, b1, W2, b2, t2s, out, n);
        k_s2_split<<<ncb * SPL, BT, 0, stream>>>(tmp, basec, cntc, t2s, xs4, out, n);
    }
}